// Round 15
// baseline (200.270 us; speedup 1.0000x reference)
//
#include <hip/hip_runtime.h>

typedef short s16x8 __attribute__((ext_vector_type(8)));
typedef float f32x4 __attribute__((ext_vector_type(4)));
typedef unsigned short u16x4 __attribute__((ext_vector_type(4)));

static __device__ __forceinline__ unsigned short f2bf(float f) {
    union { float f; unsigned u; } v; v.f = f;
    unsigned r = v.u + 0x7FFF + ((v.u >> 16) & 1);   // round-nearest-even
    return (unsigned short)(r >> 16);
}

// ---------------------------------------------------------------------------
// k_prep (massively-parallel, proven):
//  bx<1024   : btab[pr][jp][n=oc*4+ih*2+jc][k'=64] bf16 union-K LC table
//  1024..1087: Wb = bf16(w_fc1) (256,4096)
//  bx==1088  : wt_g = bf16 w_conv packed [kk][oc][ic-pad40]
// ---------------------------------------------------------------------------
__global__ __launch_bounds__(256) void k_prep(
    const float* __restrict__ w_lc, const float* __restrict__ b_lc,
    const float* __restrict__ w_conv, const float* __restrict__ w_fc1,
    unsigned short* __restrict__ btab, unsigned short* __restrict__ wt_g,
    unsigned short* __restrict__ Wb)
{
    const int t = threadIdx.x, bx = blockIdx.x;
    if (bx < 1024) {
        const int gid = bx * 256 + t;          // 0..262143, one 8-k' oct each
        const int k8 = gid & 7;
        const int nn = (gid >> 3) & 127;
        const int jp = (gid >> 10) & 15;
        const int pr = gid >> 14;
        const int o = nn >> 2, ih = (nn >> 1) & 1, jc = nn & 1;
        const int row = 2 * pr + ih, col = 2 * jp + jc;
        unsigned v32[8];
        #pragma unroll
        for (int e = 0; e < 8; ++e) {
            const int k = k8 * 8 + e;
            float v = 0.f;
            if (k < 48) {
                const int c = k >> 4, rr = (k >> 2) & 3, cf = k & 3;
                const int di = rr - ih, dj = cf - jc;
                if ((unsigned)di < 3u && (unsigned)dj < 3u)
                    v = w_lc[((o * 3 + c) * 9 + di * 3 + dj) * 1024 + row * 32 + col];
            } else if (k == 63) {
                v = b_lc[o * 1024 + row * 32 + col];
            }
            v32[e] = f2bf(v);
        }
        uint4 w;
        w.x = v32[0] | (v32[1] << 16);
        w.y = v32[2] | (v32[3] << 16);
        w.z = v32[4] | (v32[5] << 16);
        w.w = v32[6] | (v32[7] << 16);
        *(uint4*)&btab[(size_t)gid * 8] = w;
    } else if (bx < 1088) {
        const float4* wf4 = (const float4*)w_fc1;
        for (int f = t; f < 4096; f += 256) {
            const int idx = (bx - 1024) * 4096 + f;
            const float4 v = wf4[idx];
            u16x4 o = { f2bf(v.x), f2bf(v.y), f2bf(v.z), f2bf(v.w) };
            *(u16x4*)&Wb[idx * 4] = o;
        }
    } else {
        for (int i = t; i < 9 * 64 * 40; i += 256) wt_g[i] = 0;
        __syncthreads();
        for (int i = t; i < 64 * 32 * 9; i += 256) {
            const int oc = i / 288;
            const int rem = i - oc * 288;
            const int ic = rem / 9;
            const int kk = rem - ic * 9;
            wt_g[(kk * 64 + oc) * 40 + ic] = f2bf(w_conv[i]);
        }
    }
}

// ---------------------------------------------------------------------------
// k_lc: union-K MFMA LC. Block = 64 imgs x 1 pooled row. Epilogue: single
// self-contained asm block (cvt_pk_bf16 -> DPP quad pk_max_i16 pool ->
// cndmask/alignbit redistribute -> pk_max vs 0 relu) with explicit s_nop 1
// DPP hazard slots. (R8's corruption was compiler-DPP fed by asm outputs;
// here the whole sequence is one asm block, hazards managed manually.)
// i16-max on bf16 bits is exact for the pooled+relu'd result: positives are
// bit-monotone, and any mis-ordered negatives are erased by max(x,0).
// ---------------------------------------------------------------------------
__global__ __launch_bounds__(256) void k_lc(
    const float* __restrict__ x,             // half (2048,3,32,32)
    const unsigned short* __restrict__ btab, // (16,16,128,64) bf16
    unsigned short* __restrict__ y1g)        // half (2048,16,16,32) bf16
{
    __shared__ unsigned short xb_raw[8 + 12 * 67 * 34 + 8];  // zero guards, 54.7KB
    __shared__ __align__(16) unsigned short pbuf[64][40];    // 5.1 KB
    const int t = threadIdx.x;
    const int ib = blockIdx.x >> 4;          // 0..31
    const int pr = blockIdx.x & 15;
    const int img0 = ib * 64;
    unsigned short* xbp = xb_raw + 8;

    for (int f = t; f < (8 + 12 * 67 * 34 + 8) / 2; f += 256) ((int*)xb_raw)[f] = 0;
    __syncthreads();
    // stage rows 2pr-1..2pr+2 of 64 imgs as bf16 [c*4+rr][imgl(17-grouped,67)][col34]
    #pragma unroll
    for (int i = 0; i < 24; ++i) {
        const int f = t + i * 256;           // 0..6143 float4 units
        const int img = f / 96;
        const int rem = f - img * 96;
        const int c = rem >> 5, rr = (rem >> 3) & 3, cf = rem & 7;
        const int xrow = 2 * pr - 1 + rr;
        if ((unsigned)xrow < 32u) {
            const float4 v = *(const float4*)&x[
                ((size_t)(img0 + img) * 3 + c) * 1024 + xrow * 32 + cf * 4];
            const unsigned w0 = (unsigned)f2bf(v.x) | ((unsigned)f2bf(v.y) << 16);
            const unsigned w1 = (unsigned)f2bf(v.z) | ((unsigned)f2bf(v.w) << 16);
            const int imgl = (img & 15) + (img >> 4) * 17;   // 0..66
            const int sa = ((c * 4 + rr) * 67 + imgl) * 34 + cf * 4;
            *(unsigned*)&xbp[sa] = w0;
            *(unsigned*)&xbp[sa + 2] = w1;
        }
    }
    __syncthreads();

    const int lane = t & 63, wv = t >> 6;
    const int lc = lane & 15, lg = lane >> 4;
    const int shamt = (lc & 1) << 4;
    const unsigned long long m2 = __ballot(lc & 2);   // lanes taking the P1 word
    const unsigned short* bpb = btab + (((size_t)pr * 16) * 128 + wv * 32) * 64;

    // kf=1 clamped rows (fixed per lane)
    const int r1a = (8 + lg * 2 > 11) ? 11 : 8 + lg * 2;
    const int r1b = (9 + lg * 2 > 11) ? 11 : 9 + lg * 2;

    // per-wave flush base: lane = img, this wave's 8 ocs
    unsigned short* ybase = y1g + (((size_t)(img0 + lane) * 256) + pr * 16) * 32 + wv * 8;

#define ABUILD(wout, row0, row1, mbase, colb2, biasfix)                        \
    {                                                                          \
        const int rows_[2] = { row0, row1 };                                   \
        _Pragma("unroll")                                                      \
        for (int rI = 0; rI < 2; ++rI) {                                       \
            const int base = (rows_[rI] * 67 + (mbase)) * 34 + (colb2);        \
            const unsigned d0 = *(const unsigned*)&xbp[base];                  \
            const unsigned d1 = *(const unsigned*)&xbp[base + 2];              \
            const unsigned d2 = *(const unsigned*)&xbp[base + 4];              \
            wout[rI * 2 + 0] = (unsigned)(((((unsigned long long)d1) << 32) | d0) >> 16); \
            wout[rI * 2 + 1] = (unsigned)(((((unsigned long long)d2) << 32) | d1) >> 16); \
        }                                                                      \
        if (biasfix && lg == 3) wout[3] = 0x3F800000u;                         \
    }

    for (int jp = 0; jp < 16; ++jp) {
        const int colb2 = jp * 2 - 2;
        // B frags for this jp (L2-hot btab); shared across all 4 mh groups
        const unsigned short* bp = bpb + (size_t)jp * (128 * 64);
        const s16x8 B0 = *(const s16x8*)&bp[lc * 64 + lg * 8];
        const s16x8 B1 = *(const s16x8*)&bp[(16 + lc) * 64 + lg * 8];
        const s16x8 B2 = *(const s16x8*)&bp[lc * 64 + 32 + lg * 8];
        const s16x8 B3 = *(const s16x8*)&bp[(16 + lc) * 64 + 32 + lg * 8];

        #pragma unroll
        for (int mh = 0; mh < 4; ++mh) {
            const int mbase = mh * 17 + lc;
            unsigned wa[4], wb[4];
            ABUILD(wa, lg * 2, lg * 2 + 1, mbase, colb2, 0)
            ABUILD(wb, r1a, r1b, mbase, colb2, 1)
            uint4 ai = { wa[0], wa[1], wa[2], wa[3] };
            uint4 bi = { wb[0], wb[1], wb[2], wb[3] };
            const s16x8 a0 = __builtin_bit_cast(s16x8, ai);
            const s16x8 a1 = __builtin_bit_cast(s16x8, bi);

            f32x4 acc[2];
            {
                f32x4 z = {0.f, 0.f, 0.f, 0.f};
                acc[0] = z; acc[1] = z;
            }
            acc[0] = __builtin_amdgcn_mfma_f32_16x16x32_bf16(a0, B0, acc[0], 0, 0, 0);
            acc[1] = __builtin_amdgcn_mfma_f32_16x16x32_bf16(a0, B1, acc[1], 0, 0, 0);
            acc[0] = __builtin_amdgcn_mfma_f32_16x16x32_bf16(a1, B2, acc[0], 0, 0, 0);
            acc[1] = __builtin_amdgcn_mfma_f32_16x16x32_bf16(a1, B3, acc[1], 0, 0, 0);

            // pool(quad)+relu+bf16 epilogue: one asm block, manual DPP hazards
            #pragma unroll
            for (int nf = 0; nf < 2; ++nf) {
                unsigned res, p1t, q0t, q1t;
                asm("v_cvt_pk_bf16_f32 %0, %4, %5\n\t"
                    "v_cvt_pk_bf16_f32 %1, %6, %7\n\t"
                    "s_nop 1\n\t"
                    "v_mov_b32 %2, %0 quad_perm:[1,0,3,2] row_mask:0xf bank_mask:0xf\n\t"
                    "v_mov_b32 %3, %1 quad_perm:[1,0,3,2] row_mask:0xf bank_mask:0xf\n\t"
                    "v_pk_max_i16 %0, %0, %2\n\t"
                    "v_pk_max_i16 %1, %1, %3\n\t"
                    "s_nop 1\n\t"
                    "v_mov_b32 %2, %0 quad_perm:[2,3,0,1] row_mask:0xf bank_mask:0xf\n\t"
                    "v_mov_b32 %3, %1 quad_perm:[2,3,0,1] row_mask:0xf bank_mask:0xf\n\t"
                    "v_pk_max_i16 %0, %0, %2\n\t"
                    "v_pk_max_i16 %1, %1, %3\n\t"
                    "v_cndmask_b32 %0, %0, %1, %9\n\t"
                    "v_alignbit_b32 %0, %0, %0, %8\n\t"
                    "v_pk_max_i16 %0, %0, 0"
                    : "=&v"(res), "=&v"(p1t), "=&v"(q0t), "=&v"(q1t)
                    : "v"(acc[nf][0]), "v"(acc[nf][1]),
                      "v"(acc[nf][2]), "v"(acc[nf][3]),
                      "v"(shamt), "s"(m2));
                pbuf[mh * 16 + lg * 4 + (lc & 3)][wv * 8 + nf * 4 + (lc >> 2)] =
                    (unsigned short)res;
            }
        }
        // per-wave flush (NO barrier): lane = img, this wave's own 8 ocs
        *(s16x8*)&ybase[(size_t)jp * 32] = *(const s16x8*)&pbuf[lane][wv * 8];
    }
#undef ABUILD
}

// ---------------------------------------------------------------------------
// k_conv: 3x3 SAME conv (32->64) + bias + ReLU + maxpool2, bf16 MFMA.
// ---------------------------------------------------------------------------
__global__ __launch_bounds__(256, 3) void k_conv(
    const unsigned short* __restrict__ y1g,  // half (2048,16,16,32) bf16
    const unsigned short* __restrict__ wt_g, // (9,64,40) bf16 packed
    const float* __restrict__ b_conv,        // (64,)
    unsigned short* __restrict__ p2)         // half (2048,64,8,8) bf16
{
    __shared__ __align__(16) unsigned short y1t[18][18][40]; // 25,920 B
    __shared__ __align__(16) unsigned short pbuf[4][1024];   //  8,192 B
    const int t = threadIdx.x;
    const int img = blockIdx.x;

    {
        const s16x8 z = {0, 0, 0, 0, 0, 0, 0, 0};
        unsigned short* p = &y1t[0][0][0];
        for (int i = t * 8; i < 18 * 18 * 40; i += 2048) *(s16x8*)(p + i) = z;
    }
    __syncthreads();
    {
        const int prr = t >> 4, pcc = t & 15;
        const unsigned short* src = y1g + ((size_t)img * 256 + t) * 32;
        unsigned short* d = &y1t[prr + 1][pcc + 1][0];
        #pragma unroll
        for (int ch = 0; ch < 4; ++ch)
            *(s16x8*)(d + ch * 8) = *(const s16x8*)(src + ch * 8);
    }
    __syncthreads();

    const int w = t >> 6, lane = t & 63;
    const int lc = lane & 15, lg = lane >> 4;

    f32x4 acc[4][4];
    #pragma unroll
    for (int mf = 0; mf < 4; ++mf)
        #pragma unroll
        for (int nf = 0; nf < 4; ++nf) {
            f32x4 zz = {0.f, 0.f, 0.f, 0.f};
            acc[mf][nf] = zz;
        }
    #pragma unroll
    for (int kk = 0; kk < 9; ++kk) {
        const int di = kk / 3, dj = kk % 3;
        s16x8 a[4], bb[4];
        #pragma unroll
        for (int nf = 0; nf < 4; ++nf)
            bb[nf] = *(const s16x8*)&wt_g[(kk * 64 + nf * 16 + lc) * 40 + lg * 8];
        #pragma unroll
        for (int mf = 0; mf < 4; ++mf)
            a[mf] = *(const s16x8*)&y1t[w * 4 + mf + di][lc + dj][lg * 8];
        #pragma unroll
        for (int mf = 0; mf < 4; ++mf)
            #pragma unroll
            for (int nf = 0; nf < 4; ++nf)
                acc[mf][nf] = __builtin_amdgcn_mfma_f32_16x16x32_bf16(
                    a[mf], bb[nf], acc[mf][nf], 0, 0, 0);
    }
    #pragma unroll
    for (int mfp = 0; mfp < 2; ++mfp) {
        #pragma unroll
        for (int nf = 0; nf < 4; ++nf) {
            const f32x4 u = acc[mfp * 2][nf], v = acc[mfp * 2 + 1][nf];
            const float bbv = b_conv[nf * 16 + lc];
            float q0 = fmaxf(fmaxf(u[0], u[1]), fmaxf(v[0], v[1]));
            float q1 = fmaxf(fmaxf(u[2], u[3]), fmaxf(v[2], v[3]));
            q0 = fmaxf(q0 + bbv, 0.f);
            q1 = fmaxf(q1 + bbv, 0.f);
            *(unsigned*)&pbuf[w][(nf * 16 + lc) * 16 + mfp * 8 + lg * 2] =
                (unsigned)f2bf(q0) | ((unsigned)f2bf(q1) << 16);
        }
    }
    #pragma unroll
    for (int jj = 0; jj < 2; ++jj) {
        const int u8 = jj * 64 + lane;
        const int oc = u8 >> 1, s = (u8 & 1) * 8;
        const s16x8 val = *(const s16x8*)&pbuf[w][u8 * 8];
        *(s16x8*)&p2[((size_t)img * 64 + oc) * 64 + w * 16 + s] = val;
    }
}

// ---------------------------------------------------------------------------
// k_fc1: SplitK=2 partial GEMM, BN=64 (A re-read traffic halved vs BN=32).
// fc1p[z][4096][256] f32 (bias in z=0, no relu).
// ---------------------------------------------------------------------------
__global__ __launch_bounds__(256) void k_fc1(
    const unsigned short* __restrict__ A,   // (4096,4096) bf16
    const unsigned short* __restrict__ Wb,  // (256,4096) bf16
    const float* __restrict__ bias, float* __restrict__ fc1p)
{
    __shared__ __align__(16) unsigned short As[64][72];
    __shared__ __align__(16) unsigned short Bs[64][72];
    const int t = threadIdx.x;
    const int m0 = blockIdx.x * 64, n0 = blockIdx.y * 64;
    const int z = blockIdx.z;
    const int w = t >> 6, lane = t & 63;
    const int lc = lane & 15, lg = lane >> 4;
    f32x4 acc[4];
    #pragma unroll
    for (int nf = 0; nf < 4; ++nf) {
        const float bv = (z == 0) ? bias[n0 + nf * 16 + lc] : 0.f;
        f32x4 a0 = {bv, bv, bv, bv};
        acc[nf] = a0;
    }
    const int kbase = z * 2048;
    const int r0 = t >> 3, ch0 = (t & 7) * 8;
    for (int k0 = kbase; k0 < kbase + 2048; k0 += 64) {
        *(s16x8*)&As[r0][ch0]      = *(const s16x8*)&A[(size_t)(m0 + r0) * 4096 + k0 + ch0];
        *(s16x8*)&As[r0 + 32][ch0] = *(const s16x8*)&A[(size_t)(m0 + r0 + 32) * 4096 + k0 + ch0];
        *(s16x8*)&Bs[r0][ch0]      = *(const s16x8*)&Wb[(size_t)(n0 + r0) * 4096 + k0 + ch0];
        *(s16x8*)&Bs[r0 + 32][ch0] = *(const s16x8*)&Wb[(size_t)(n0 + r0 + 32) * 4096 + k0 + ch0];
        __syncthreads();
        #pragma unroll
        for (int kh = 0; kh < 2; ++kh) {
            const s16x8 a = *(const s16x8*)&As[w * 16 + lc][kh * 32 + lg * 8];
            #pragma unroll
            for (int nf = 0; nf < 4; ++nf) {
                const s16x8 b = *(const s16x8*)&Bs[nf * 16 + lc][kh * 32 + lg * 8];
                acc[nf] = __builtin_amdgcn_mfma_f32_16x16x32_bf16(a, b, acc[nf], 0, 0, 0);
            }
        }
        __syncthreads();
    }
    #pragma unroll
    for (int nf = 0; nf < 4; ++nf) {
        const int n = n0 + nf * 16 + lc;
        #pragma unroll
        for (int q = 0; q < 4; ++q) {
            const int m = m0 + w * 16 + lg * 4 + q;
            fc1p[((size_t)z * 4096 + m) * 256 + n] = acc[nf][q];
        }
    }
}

// ---------------------------------------------------------------------------
// k_fc2: out = relu(fc1p[0]+fc1p[1]) @ w_fc2^T + b
// ---------------------------------------------------------------------------
__global__ __launch_bounds__(320) void k_fc2(
    const float* __restrict__ fc1p, const float* __restrict__ Wt,
    const float* __restrict__ bias, float* __restrict__ out)
{
    const int t = threadIdx.x;
    const int r = blockIdx.x * 32 + t / 10;
    const int n = t % 10;
    const float4* a0 = (const float4*)(fc1p + (size_t)r * 256);
    const float4* a1 = (const float4*)(fc1p + (size_t)(4096 + r) * 256);
    const float4* w = (const float4*)(Wt + (size_t)n * 256);
    float acc = bias[n];
    #pragma unroll 8
    for (int k = 0; k < 64; ++k) {
        const float4 u = a0[k], v = a1[k], wv = w[k];
        acc += fmaxf(u.x + v.x, 0.f) * wv.x + fmaxf(u.y + v.y, 0.f) * wv.y +
               fmaxf(u.z + v.z, 0.f) * wv.z + fmaxf(u.w + v.w, 0.f) * wv.w;
    }
    out[(size_t)r * 10 + n] = acc;
}

extern "C" void kernel_launch(void* const* d_in, const int* in_sizes, int n_in,
                              void* d_out, int out_size, void* d_ws, size_t ws_size,
                              hipStream_t stream)
{
    const float* x      = (const float*)d_in[0];
    const float* w_lc   = (const float*)d_in[1];
    const float* b_lc   = (const float*)d_in[2];
    const float* w_conv = (const float*)d_in[3];
    const float* b_conv = (const float*)d_in[4];
    const float* w_fc1  = (const float*)d_in[5];
    const float* b_fc1  = (const float*)d_in[6];
    const float* w_fc2  = (const float*)d_in[7];
    const float* b_fc2  = (const float*)d_in[8];
    float* out = (float*)d_out;

    // ws layout (69.3 MB total, proven):
    //   p2b  @ 0          : 33,554,432  (4096x4096 bf16)
    //   btab @ 16,777,216 : 4,194,304   (inside p2b 2nd half; clobbered by
    //                                    k_conv half1 only AFTER last btab read)
    //   y1g  @ 33,554,432 : 33,554,432  (half 2048x16x16x32 bf16)
    //   fc1p @ 33,554,432 : 8,388,608 f32 x2 partials (aliases y1g; post-conv)
    //   Wb   @ 67,108,864 : 2,097,152
    //   wt_g @ 69,206,016 : 92,160
    unsigned short* p2b  = (unsigned short*)d_ws;
    unsigned short* btab = (unsigned short*)((char*)d_ws + 16777216);
    unsigned short* y1g  = (unsigned short*)((char*)d_ws + 33554432);
    float*          fc1p = (float*)((char*)d_ws + 33554432);
    unsigned short* Wb   = (unsigned short*)((char*)d_ws + 67108864);
    unsigned short* wt_g = (unsigned short*)((char*)d_ws + 69206016);

    k_prep<<<1089, 256, 0, stream>>>(w_lc, b_lc, w_conv, w_fc1, btab, wt_g, Wb);
    for (int half = 0; half < 2; ++half) {
        k_lc<<<512, 256, 0, stream>>>(x + (size_t)half * 2048 * 3072, btab, y1g);
        k_conv<<<2048, 256, 0, stream>>>(y1g, wt_g, b_conv,
                                         p2b + (size_t)half * 2048 * 4096);
    }
    k_fc1<<<dim3(64, 4, 2), 256, 0, stream>>>(p2b, Wb, b_fc1, fc1p);
    k_fc2<<<128, 320, 0, stream>>>(fc1p, w_fc2, b_fc2, out);
}

// Round 17
// 175.230 us; speedup vs baseline: 1.1429x; 1.1429x over previous
//
#include <hip/hip_runtime.h>

typedef short s16x8 __attribute__((ext_vector_type(8)));
typedef float f32x4 __attribute__((ext_vector_type(4)));
typedef unsigned short u16x4 __attribute__((ext_vector_type(4)));

static __device__ __forceinline__ unsigned short f2bf(float f) {
    union { float f; unsigned u; } v; v.f = f;
    unsigned r = v.u + 0x7FFF + ((v.u >> 16) & 1);   // round-nearest-even
    return (unsigned short)(r >> 16);
}

// ---------------------------------------------------------------------------
// k_prep (massively-parallel, proven):
//  bx<1024   : btab[pr][jp][n=oc*4+ih*2+jc][k'=64] bf16 union-K LC table
//  1024..1087: Wb = bf16(w_fc1) (256,4096)
//  bx==1088  : wt_g = bf16 w_conv packed [kk][oc][ic-pad40]
// ---------------------------------------------------------------------------
__global__ __launch_bounds__(256) void k_prep(
    const float* __restrict__ w_lc, const float* __restrict__ b_lc,
    const float* __restrict__ w_conv, const float* __restrict__ w_fc1,
    unsigned short* __restrict__ btab, unsigned short* __restrict__ wt_g,
    unsigned short* __restrict__ Wb)
{
    const int t = threadIdx.x, bx = blockIdx.x;
    if (bx < 1024) {
        const int gid = bx * 256 + t;          // 0..262143, one 8-k' oct each
        const int k8 = gid & 7;
        const int nn = (gid >> 3) & 127;
        const int jp = (gid >> 10) & 15;
        const int pr = gid >> 14;
        const int o = nn >> 2, ih = (nn >> 1) & 1, jc = nn & 1;
        const int row = 2 * pr + ih, col = 2 * jp + jc;
        unsigned v32[8];
        #pragma unroll
        for (int e = 0; e < 8; ++e) {
            const int k = k8 * 8 + e;
            float v = 0.f;
            if (k < 48) {
                const int c = k >> 4, rr = (k >> 2) & 3, cf = k & 3;
                const int di = rr - ih, dj = cf - jc;
                if ((unsigned)di < 3u && (unsigned)dj < 3u)
                    v = w_lc[((o * 3 + c) * 9 + di * 3 + dj) * 1024 + row * 32 + col];
            } else if (k == 63) {
                v = b_lc[o * 1024 + row * 32 + col];
            }
            v32[e] = f2bf(v);
        }
        uint4 w;
        w.x = v32[0] | (v32[1] << 16);
        w.y = v32[2] | (v32[3] << 16);
        w.z = v32[4] | (v32[5] << 16);
        w.w = v32[6] | (v32[7] << 16);
        *(uint4*)&btab[(size_t)gid * 8] = w;
    } else if (bx < 1088) {
        const float4* wf4 = (const float4*)w_fc1;
        for (int f = t; f < 4096; f += 256) {
            const int idx = (bx - 1024) * 4096 + f;
            const float4 v = wf4[idx];
            u16x4 o = { f2bf(v.x), f2bf(v.y), f2bf(v.z), f2bf(v.w) };
            *(u16x4*)&Wb[idx * 4] = o;
        }
    } else {
        for (int i = t; i < 9 * 64 * 40; i += 256) wt_g[i] = 0;
        __syncthreads();
        for (int i = t; i < 64 * 32 * 9; i += 256) {
            const int oc = i / 288;
            const int rem = i - oc * 288;
            const int ic = rem / 9;
            const int kk = rem - ic * 9;
            wt_g[(kk * 64 + oc) * 40 + ic] = f2bf(w_conv[i]);
        }
    }
}

// ---------------------------------------------------------------------------
// k_lc: union-K MFMA LC. Block = 64 imgs x 1 pooled row. Epilogue: single
// self-contained asm block (cvt_pk_bf16 -> DPP quad pk_max_i16 pool ->
// cndmask/alignbit redistribute -> pk_max vs 0 relu) with explicit s_nop 1
// DPP hazard slots. Verified passing incl. post-timing in R15.
// ---------------------------------------------------------------------------
__global__ __launch_bounds__(256) void k_lc(
    const float* __restrict__ x,             // half (2048,3,32,32)
    const unsigned short* __restrict__ btab, // (16,16,128,64) bf16
    unsigned short* __restrict__ y1g)        // half (2048,16,16,32) bf16
{
    __shared__ unsigned short xb_raw[8 + 12 * 67 * 34 + 8];  // zero guards, 54.7KB
    __shared__ __align__(16) unsigned short pbuf[64][40];    // 5.1 KB
    const int t = threadIdx.x;
    const int ib = blockIdx.x >> 4;          // 0..31
    const int pr = blockIdx.x & 15;
    const int img0 = ib * 64;
    unsigned short* xbp = xb_raw + 8;

    for (int f = t; f < (8 + 12 * 67 * 34 + 8) / 2; f += 256) ((int*)xb_raw)[f] = 0;
    __syncthreads();
    // stage rows 2pr-1..2pr+2 of 64 imgs as bf16 [c*4+rr][imgl(17-grouped,67)][col34]
    #pragma unroll
    for (int i = 0; i < 24; ++i) {
        const int f = t + i * 256;           // 0..6143 float4 units
        const int img = f / 96;
        const int rem = f - img * 96;
        const int c = rem >> 5, rr = (rem >> 3) & 3, cf = rem & 7;
        const int xrow = 2 * pr - 1 + rr;
        if ((unsigned)xrow < 32u) {
            const float4 v = *(const float4*)&x[
                ((size_t)(img0 + img) * 3 + c) * 1024 + xrow * 32 + cf * 4];
            const unsigned w0 = (unsigned)f2bf(v.x) | ((unsigned)f2bf(v.y) << 16);
            const unsigned w1 = (unsigned)f2bf(v.z) | ((unsigned)f2bf(v.w) << 16);
            const int imgl = (img & 15) + (img >> 4) * 17;   // 0..66
            const int sa = ((c * 4 + rr) * 67 + imgl) * 34 + cf * 4;
            *(unsigned*)&xbp[sa] = w0;
            *(unsigned*)&xbp[sa + 2] = w1;
        }
    }
    __syncthreads();

    const int lane = t & 63, wv = t >> 6;
    const int lc = lane & 15, lg = lane >> 4;
    const int shamt = (lc & 1) << 4;
    const unsigned long long m2 = __ballot(lc & 2);   // lanes taking the P1 word
    const unsigned short* bpb = btab + (((size_t)pr * 16) * 128 + wv * 32) * 64;

    // kf=1 clamped rows (fixed per lane)
    const int r1a = (8 + lg * 2 > 11) ? 11 : 8 + lg * 2;
    const int r1b = (9 + lg * 2 > 11) ? 11 : 9 + lg * 2;

    // per-wave flush base: lane = img, this wave's 8 ocs
    unsigned short* ybase = y1g + (((size_t)(img0 + lane) * 256) + pr * 16) * 32 + wv * 8;

#define ABUILD(wout, row0, row1, mbase, colb2, biasfix)                        \
    {                                                                          \
        const int rows_[2] = { row0, row1 };                                   \
        _Pragma("unroll")                                                      \
        for (int rI = 0; rI < 2; ++rI) {                                       \
            const int base = (rows_[rI] * 67 + (mbase)) * 34 + (colb2);        \
            const unsigned d0 = *(const unsigned*)&xbp[base];                  \
            const unsigned d1 = *(const unsigned*)&xbp[base + 2];              \
            const unsigned d2 = *(const unsigned*)&xbp[base + 4];              \
            wout[rI * 2 + 0] = (unsigned)(((((unsigned long long)d1) << 32) | d0) >> 16); \
            wout[rI * 2 + 1] = (unsigned)(((((unsigned long long)d2) << 32) | d1) >> 16); \
        }                                                                      \
        if (biasfix && lg == 3) wout[3] = 0x3F800000u;                         \
    }

    for (int jp = 0; jp < 16; ++jp) {
        const int colb2 = jp * 2 - 2;
        // B frags for this jp (L2-hot btab); shared across all 4 mh groups
        const unsigned short* bp = bpb + (size_t)jp * (128 * 64);
        const s16x8 B0 = *(const s16x8*)&bp[lc * 64 + lg * 8];
        const s16x8 B1 = *(const s16x8*)&bp[(16 + lc) * 64 + lg * 8];
        const s16x8 B2 = *(const s16x8*)&bp[lc * 64 + 32 + lg * 8];
        const s16x8 B3 = *(const s16x8*)&bp[(16 + lc) * 64 + 32 + lg * 8];

        #pragma unroll
        for (int mh = 0; mh < 4; ++mh) {
            const int mbase = mh * 17 + lc;
            unsigned wa[4], wb[4];
            ABUILD(wa, lg * 2, lg * 2 + 1, mbase, colb2, 0)
            ABUILD(wb, r1a, r1b, mbase, colb2, 1)
            uint4 ai = { wa[0], wa[1], wa[2], wa[3] };
            uint4 bi = { wb[0], wb[1], wb[2], wb[3] };
            const s16x8 a0 = __builtin_bit_cast(s16x8, ai);
            const s16x8 a1 = __builtin_bit_cast(s16x8, bi);

            f32x4 acc[2];
            {
                f32x4 z = {0.f, 0.f, 0.f, 0.f};
                acc[0] = z; acc[1] = z;
            }
            acc[0] = __builtin_amdgcn_mfma_f32_16x16x32_bf16(a0, B0, acc[0], 0, 0, 0);
            acc[1] = __builtin_amdgcn_mfma_f32_16x16x32_bf16(a0, B1, acc[1], 0, 0, 0);
            acc[0] = __builtin_amdgcn_mfma_f32_16x16x32_bf16(a1, B2, acc[0], 0, 0, 0);
            acc[1] = __builtin_amdgcn_mfma_f32_16x16x32_bf16(a1, B3, acc[1], 0, 0, 0);

            // pool(quad)+relu+bf16 epilogue: one asm block, manual DPP hazards
            #pragma unroll
            for (int nf = 0; nf < 2; ++nf) {
                unsigned res, p1t, q0t, q1t;
                asm("v_cvt_pk_bf16_f32 %0, %4, %5\n\t"
                    "v_cvt_pk_bf16_f32 %1, %6, %7\n\t"
                    "s_nop 1\n\t"
                    "v_mov_b32 %2, %0 quad_perm:[1,0,3,2] row_mask:0xf bank_mask:0xf\n\t"
                    "v_mov_b32 %3, %1 quad_perm:[1,0,3,2] row_mask:0xf bank_mask:0xf\n\t"
                    "v_pk_max_i16 %0, %0, %2\n\t"
                    "v_pk_max_i16 %1, %1, %3\n\t"
                    "s_nop 1\n\t"
                    "v_mov_b32 %2, %0 quad_perm:[2,3,0,1] row_mask:0xf bank_mask:0xf\n\t"
                    "v_mov_b32 %3, %1 quad_perm:[2,3,0,1] row_mask:0xf bank_mask:0xf\n\t"
                    "v_pk_max_i16 %0, %0, %2\n\t"
                    "v_pk_max_i16 %1, %1, %3\n\t"
                    "v_cndmask_b32 %0, %0, %1, %9\n\t"
                    "v_alignbit_b32 %0, %0, %0, %8\n\t"
                    "v_pk_max_i16 %0, %0, 0"
                    : "=&v"(res), "=&v"(p1t), "=&v"(q0t), "=&v"(q1t)
                    : "v"(acc[nf][0]), "v"(acc[nf][1]),
                      "v"(acc[nf][2]), "v"(acc[nf][3]),
                      "v"(shamt), "s"(m2));
                pbuf[mh * 16 + lg * 4 + (lc & 3)][wv * 8 + nf * 4 + (lc >> 2)] =
                    (unsigned short)res;
            }
        }
        // per-wave flush (NO barrier): lane = img, this wave's own 8 ocs
        *(s16x8*)&ybase[(size_t)jp * 32] = *(const s16x8*)&pbuf[lane][wv * 8];
    }
#undef ABUILD
}

// ---------------------------------------------------------------------------
// k_conv: 3x3 SAME conv (32->64) + bias + ReLU + maxpool2, bf16 MFMA.
// ---------------------------------------------------------------------------
__global__ __launch_bounds__(256, 3) void k_conv(
    const unsigned short* __restrict__ y1g,  // half (2048,16,16,32) bf16
    const unsigned short* __restrict__ wt_g, // (9,64,40) bf16 packed
    const float* __restrict__ b_conv,        // (64,)
    unsigned short* __restrict__ p2)         // half (2048,64,8,8) bf16
{
    __shared__ __align__(16) unsigned short y1t[18][18][40]; // 25,920 B
    __shared__ __align__(16) unsigned short pbuf[4][1024];   //  8,192 B
    const int t = threadIdx.x;
    const int img = blockIdx.x;

    {
        const s16x8 z = {0, 0, 0, 0, 0, 0, 0, 0};
        unsigned short* p = &y1t[0][0][0];
        for (int i = t * 8; i < 18 * 18 * 40; i += 2048) *(s16x8*)(p + i) = z;
    }
    __syncthreads();
    {
        const int prr = t >> 4, pcc = t & 15;
        const unsigned short* src = y1g + ((size_t)img * 256 + t) * 32;
        unsigned short* d = &y1t[prr + 1][pcc + 1][0];
        #pragma unroll
        for (int ch = 0; ch < 4; ++ch)
            *(s16x8*)(d + ch * 8) = *(const s16x8*)(src + ch * 8);
    }
    __syncthreads();

    const int w = t >> 6, lane = t & 63;
    const int lc = lane & 15, lg = lane >> 4;

    f32x4 acc[4][4];
    #pragma unroll
    for (int mf = 0; mf < 4; ++mf)
        #pragma unroll
        for (int nf = 0; nf < 4; ++nf) {
            f32x4 zz = {0.f, 0.f, 0.f, 0.f};
            acc[mf][nf] = zz;
        }
    #pragma unroll
    for (int kk = 0; kk < 9; ++kk) {
        const int di = kk / 3, dj = kk % 3;
        s16x8 a[4], bb[4];
        #pragma unroll
        for (int nf = 0; nf < 4; ++nf)
            bb[nf] = *(const s16x8*)&wt_g[(kk * 64 + nf * 16 + lc) * 40 + lg * 8];
        #pragma unroll
        for (int mf = 0; mf < 4; ++mf)
            a[mf] = *(const s16x8*)&y1t[w * 4 + mf + di][lc + dj][lg * 8];
        #pragma unroll
        for (int mf = 0; mf < 4; ++mf)
            #pragma unroll
            for (int nf = 0; nf < 4; ++nf)
                acc[mf][nf] = __builtin_amdgcn_mfma_f32_16x16x32_bf16(
                    a[mf], bb[nf], acc[mf][nf], 0, 0, 0);
    }
    #pragma unroll
    for (int mfp = 0; mfp < 2; ++mfp) {
        #pragma unroll
        for (int nf = 0; nf < 4; ++nf) {
            const f32x4 u = acc[mfp * 2][nf], v = acc[mfp * 2 + 1][nf];
            const float bbv = b_conv[nf * 16 + lc];
            float q0 = fmaxf(fmaxf(u[0], u[1]), fmaxf(v[0], v[1]));
            float q1 = fmaxf(fmaxf(u[2], u[3]), fmaxf(v[2], v[3]));
            q0 = fmaxf(q0 + bbv, 0.f);
            q1 = fmaxf(q1 + bbv, 0.f);
            *(unsigned*)&pbuf[w][(nf * 16 + lc) * 16 + mfp * 8 + lg * 2] =
                (unsigned)f2bf(q0) | ((unsigned)f2bf(q1) << 16);
        }
    }
    #pragma unroll
    for (int jj = 0; jj < 2; ++jj) {
        const int u8 = jj * 64 + lane;
        const int oc = u8 >> 1, s = (u8 & 1) * 8;
        const s16x8 val = *(const s16x8*)&pbuf[w][u8 * 8];
        *(s16x8*)&p2[((size_t)img * 64 + oc) * 64 + w * 16 + s] = val;
    }
}

// ---------------------------------------------------------------------------
// k_fc1: SplitK=2 partial GEMM, BN=32 (R11-R14 post-timing-proven version).
// fc1p[z][4096][256] f32 (bias in z=0, no relu).
// ---------------------------------------------------------------------------
__global__ __launch_bounds__(256) void k_fc1(
    const unsigned short* __restrict__ A,   // (4096,4096) bf16
    const unsigned short* __restrict__ Wb,  // (256,4096) bf16
    const float* __restrict__ bias, float* __restrict__ fc1p)
{
    __shared__ __align__(16) unsigned short As[64][72];
    __shared__ __align__(16) unsigned short Bs[32][72];
    const int t = threadIdx.x;
    const int m0 = blockIdx.x * 64, n0 = blockIdx.y * 32;
    const int z = blockIdx.z;
    const int w = t >> 6, lane = t & 63;
    const int lc = lane & 15, lg = lane >> 4;
    f32x4 acc[2];
    {
        const float bv0 = (z == 0) ? bias[n0 + lc] : 0.f;
        const float bv1 = (z == 0) ? bias[n0 + 16 + lc] : 0.f;
        f32x4 a0 = {bv0, bv0, bv0, bv0}, a1 = {bv1, bv1, bv1, bv1};
        acc[0] = a0; acc[1] = a1;
    }
    const int kbase = z * 2048;
    for (int k0 = kbase; k0 < kbase + 2048; k0 += 64) {
        {
            const int r0 = t >> 3, ch0 = (t & 7) * 8;
            const int id1 = t + 256;
            const int r1 = id1 >> 3, ch1 = (id1 & 7) * 8;
            *(s16x8*)&As[r0][ch0] = *(const s16x8*)&A[(size_t)(m0 + r0) * 4096 + k0 + ch0];
            *(s16x8*)&As[r1][ch1] = *(const s16x8*)&A[(size_t)(m0 + r1) * 4096 + k0 + ch1];
            const int rb = t >> 3, cb = (t & 7) * 8;
            *(s16x8*)&Bs[rb][cb] = *(const s16x8*)&Wb[(size_t)(n0 + rb) * 4096 + k0 + cb];
        }
        __syncthreads();
        #pragma unroll
        for (int kh = 0; kh < 2; ++kh) {
            const s16x8 a  = *(const s16x8*)&As[w * 16 + lc][kh * 32 + lg * 8];
            const s16x8 b0 = *(const s16x8*)&Bs[lc][kh * 32 + lg * 8];
            const s16x8 b1 = *(const s16x8*)&Bs[16 + lc][kh * 32 + lg * 8];
            acc[0] = __builtin_amdgcn_mfma_f32_16x16x32_bf16(a, b0, acc[0], 0, 0, 0);
            acc[1] = __builtin_amdgcn_mfma_f32_16x16x32_bf16(a, b1, acc[1], 0, 0, 0);
        }
        __syncthreads();
    }
    #pragma unroll
    for (int nf = 0; nf < 2; ++nf) {
        const int n = n0 + nf * 16 + lc;
        #pragma unroll
        for (int q = 0; q < 4; ++q) {
            const int m = m0 + w * 16 + lg * 4 + q;
            fc1p[((size_t)z * 4096 + m) * 256 + n] = acc[nf][q];
        }
    }
}

// ---------------------------------------------------------------------------
// k_fc2: out = relu(fc1p[0]+fc1p[1]) @ w_fc2^T + b
// ---------------------------------------------------------------------------
__global__ __launch_bounds__(320) void k_fc2(
    const float* __restrict__ fc1p, const float* __restrict__ Wt,
    const float* __restrict__ bias, float* __restrict__ out)
{
    const int t = threadIdx.x;
    const int r = blockIdx.x * 32 + t / 10;
    const int n = t % 10;
    const float4* a0 = (const float4*)(fc1p + (size_t)r * 256);
    const float4* a1 = (const float4*)(fc1p + (size_t)(4096 + r) * 256);
    const float4* w = (const float4*)(Wt + (size_t)n * 256);
    float acc = bias[n];
    #pragma unroll 8
    for (int k = 0; k < 64; ++k) {
        const float4 u = a0[k], v = a1[k], wv = w[k];
        acc += fmaxf(u.x + v.x, 0.f) * wv.x + fmaxf(u.y + v.y, 0.f) * wv.y +
               fmaxf(u.z + v.z, 0.f) * wv.z + fmaxf(u.w + v.w, 0.f) * wv.w;
    }
    out[(size_t)r * 10 + n] = acc;
}

extern "C" void kernel_launch(void* const* d_in, const int* in_sizes, int n_in,
                              void* d_out, int out_size, void* d_ws, size_t ws_size,
                              hipStream_t stream)
{
    const float* x      = (const float*)d_in[0];
    const float* w_lc   = (const float*)d_in[1];
    const float* b_lc   = (const float*)d_in[2];
    const float* w_conv = (const float*)d_in[3];
    const float* b_conv = (const float*)d_in[4];
    const float* w_fc1  = (const float*)d_in[5];
    const float* b_fc1  = (const float*)d_in[6];
    const float* w_fc2  = (const float*)d_in[7];
    const float* b_fc2  = (const float*)d_in[8];
    float* out = (float*)d_out;

    // ws layout (69.3 MB total, proven):
    //   p2b  @ 0          : 33,554,432  (4096x4096 bf16)
    //   btab @ 16,777,216 : 4,194,304   (inside p2b 2nd half; clobbered by
    //                                    k_conv half1 only AFTER last btab read)
    //   y1g  @ 33,554,432 : 33,554,432  (half 2048x16x16x32 bf16)
    //   fc1p @ 33,554,432 : 8,388,608 f32 x2 partials (aliases y1g; post-conv)
    //   Wb   @ 67,108,864 : 2,097,152
    //   wt_g @ 69,206,016 : 92,160
    unsigned short* p2b  = (unsigned short*)d_ws;
    unsigned short* btab = (unsigned short*)((char*)d_ws + 16777216);
    unsigned short* y1g  = (unsigned short*)((char*)d_ws + 33554432);
    float*          fc1p = (float*)((char*)d_ws + 33554432);
    unsigned short* Wb   = (unsigned short*)((char*)d_ws + 67108864);
    unsigned short* wt_g = (unsigned short*)((char*)d_ws + 69206016);

    k_prep<<<1089, 256, 0, stream>>>(w_lc, b_lc, w_conv, w_fc1, btab, wt_g, Wb);
    for (int half = 0; half < 2; ++half) {
        k_lc<<<512, 256, 0, stream>>>(x + (size_t)half * 2048 * 3072, btab, y1g);
        k_conv<<<2048, 256, 0, stream>>>(y1g, wt_g, b_conv,
                                         p2b + (size_t)half * 2048 * 4096);
    }
    k_fc1<<<dim3(64, 8, 2), 256, 0, stream>>>(p2b, Wb, b_fc1, fc1p);
    k_fc2<<<128, 320, 0, stream>>>(fc1p, w_fc2, b_fc2, out);
}

// Round 18
// 172.758 us; speedup vs baseline: 1.1593x; 1.0143x over previous
//
#include <hip/hip_runtime.h>

typedef short s16x8 __attribute__((ext_vector_type(8)));
typedef float f32x4 __attribute__((ext_vector_type(4)));
typedef unsigned short u16x4 __attribute__((ext_vector_type(4)));

static __device__ __forceinline__ unsigned short f2bf(float f) {
    union { float f; unsigned u; } v; v.f = f;
    unsigned r = v.u + 0x7FFF + ((v.u >> 16) & 1);   // round-nearest-even
    return (unsigned short)(r >> 16);
}

// ---------------------------------------------------------------------------
// k_prep (massively-parallel, proven):
//  bx<1024   : btab[pr][jp][n=oc*4+ih*2+jc][k'=64] bf16 union-K LC table
//  1024..1087: Wb = bf16(w_fc1) (256,4096)
//  bx==1088  : wt_g = bf16 w_conv packed [kk][oc][ic-pad40]
// ---------------------------------------------------------------------------
__global__ __launch_bounds__(256) void k_prep(
    const float* __restrict__ w_lc, const float* __restrict__ b_lc,
    const float* __restrict__ w_conv, const float* __restrict__ w_fc1,
    unsigned short* __restrict__ btab, unsigned short* __restrict__ wt_g,
    unsigned short* __restrict__ Wb)
{
    const int t = threadIdx.x, bx = blockIdx.x;
    if (bx < 1024) {
        const int gid = bx * 256 + t;          // 0..262143, one 8-k' oct each
        const int k8 = gid & 7;
        const int nn = (gid >> 3) & 127;
        const int jp = (gid >> 10) & 15;
        const int pr = gid >> 14;
        const int o = nn >> 2, ih = (nn >> 1) & 1, jc = nn & 1;
        const int row = 2 * pr + ih, col = 2 * jp + jc;
        unsigned v32[8];
        #pragma unroll
        for (int e = 0; e < 8; ++e) {
            const int k = k8 * 8 + e;
            float v = 0.f;
            if (k < 48) {
                const int c = k >> 4, rr = (k >> 2) & 3, cf = k & 3;
                const int di = rr - ih, dj = cf - jc;
                if ((unsigned)di < 3u && (unsigned)dj < 3u)
                    v = w_lc[((o * 3 + c) * 9 + di * 3 + dj) * 1024 + row * 32 + col];
            } else if (k == 63) {
                v = b_lc[o * 1024 + row * 32 + col];
            }
            v32[e] = f2bf(v);
        }
        uint4 w;
        w.x = v32[0] | (v32[1] << 16);
        w.y = v32[2] | (v32[3] << 16);
        w.z = v32[4] | (v32[5] << 16);
        w.w = v32[6] | (v32[7] << 16);
        *(uint4*)&btab[(size_t)gid * 8] = w;
    } else if (bx < 1088) {
        const float4* wf4 = (const float4*)w_fc1;
        for (int f = t; f < 4096; f += 256) {
            const int idx = (bx - 1024) * 4096 + f;
            const float4 v = wf4[idx];
            u16x4 o = { f2bf(v.x), f2bf(v.y), f2bf(v.z), f2bf(v.w) };
            *(u16x4*)&Wb[idx * 4] = o;
        }
    } else {
        for (int i = t; i < 9 * 64 * 40; i += 256) wt_g[i] = 0;
        __syncthreads();
        for (int i = t; i < 64 * 32 * 9; i += 256) {
            const int oc = i / 288;
            const int rem = i - oc * 288;
            const int ic = rem / 9;
            const int kk = rem - ic * 9;
            wt_g[(kk * 64 + oc) * 40 + ic] = f2bf(w_conv[i]);
        }
    }
}

// ---------------------------------------------------------------------------
// k_lc: union-K MFMA LC. Block = 64 imgs x 1 pooled row, 512 threads (8
// waves): wave wv -> oc-slice (wv&3), jp-parity (wv>>2). Doubles waves/CU
// (8->16) at same per-CU work. pbuf[2 parities][64][40]; barrier-free
// per-wave flush. Asm pool epilogue proven in R15/R17.
// ---------------------------------------------------------------------------
__global__ __launch_bounds__(512) void k_lc(
    const float* __restrict__ x,             // half (2048,3,32,32)
    const unsigned short* __restrict__ btab, // (16,16,128,64) bf16
    unsigned short* __restrict__ y1g)        // half (2048,16,16,32) bf16
{
    __shared__ unsigned short xb_raw[8 + 12 * 67 * 34 + 8];  // zero guards, 54.7KB
    __shared__ __align__(16) unsigned short pbuf[2][64][40]; // 10.2 KB
    const int t = threadIdx.x;
    const int ib = blockIdx.x >> 4;          // 0..31
    const int pr = blockIdx.x & 15;
    const int img0 = ib * 64;
    unsigned short* xbp = xb_raw + 8;

    for (int f = t; f < (8 + 12 * 67 * 34 + 8) / 2; f += 512) ((int*)xb_raw)[f] = 0;
    __syncthreads();
    // stage rows 2pr-1..2pr+2 of 64 imgs as bf16 [c*4+rr][imgl(17-grouped,67)][col34]
    #pragma unroll
    for (int i = 0; i < 12; ++i) {
        const int f = t + i * 512;           // 0..6143 float4 units
        const int img = f / 96;
        const int rem = f - img * 96;
        const int c = rem >> 5, rr = (rem >> 3) & 3, cf = rem & 7;
        const int xrow = 2 * pr - 1 + rr;
        if ((unsigned)xrow < 32u) {
            const float4 v = *(const float4*)&x[
                ((size_t)(img0 + img) * 3 + c) * 1024 + xrow * 32 + cf * 4];
            const unsigned w0 = (unsigned)f2bf(v.x) | ((unsigned)f2bf(v.y) << 16);
            const unsigned w1 = (unsigned)f2bf(v.z) | ((unsigned)f2bf(v.w) << 16);
            const int imgl = (img & 15) + (img >> 4) * 17;   // 0..66
            const int sa = ((c * 4 + rr) * 67 + imgl) * 34 + cf * 4;
            *(unsigned*)&xbp[sa] = w0;
            *(unsigned*)&xbp[sa + 2] = w1;
        }
    }
    __syncthreads();

    const int lane = t & 63, wv = t >> 6;     // wv 0..7
    const int ocw = wv & 3, par = wv >> 2;    // oc-slice, jp-parity
    const int lc = lane & 15, lg = lane >> 4;
    const int shamt = (lc & 1) << 4;
    const unsigned long long m2 = __ballot(lc & 2);   // lanes taking the P1 word
    const unsigned short* bpb = btab + (((size_t)pr * 16) * 128 + ocw * 32) * 64;

    // kf=1 clamped rows (fixed per lane)
    const int r1a = (8 + lg * 2 > 11) ? 11 : 8 + lg * 2;
    const int r1b = (9 + lg * 2 > 11) ? 11 : 9 + lg * 2;

    // per-wave flush base: lane = img, this wave's 8 ocs
    unsigned short* ybase = y1g + (((size_t)(img0 + lane) * 256) + pr * 16) * 32 + ocw * 8;

#define ABUILD(wout, row0, row1, mbase, colb2, biasfix)                        \
    {                                                                          \
        const int rows_[2] = { row0, row1 };                                   \
        _Pragma("unroll")                                                      \
        for (int rI = 0; rI < 2; ++rI) {                                       \
            const int base = (rows_[rI] * 67 + (mbase)) * 34 + (colb2);        \
            const unsigned d0 = *(const unsigned*)&xbp[base];                  \
            const unsigned d1 = *(const unsigned*)&xbp[base + 2];              \
            const unsigned d2 = *(const unsigned*)&xbp[base + 4];              \
            wout[rI * 2 + 0] = (unsigned)(((((unsigned long long)d1) << 32) | d0) >> 16); \
            wout[rI * 2 + 1] = (unsigned)(((((unsigned long long)d2) << 32) | d1) >> 16); \
        }                                                                      \
        if (biasfix && lg == 3) wout[3] = 0x3F800000u;                         \
    }

    for (int jp2 = 0; jp2 < 8; ++jp2) {
        const int jp = jp2 * 2 + par;
        const int colb2 = jp * 2 - 2;
        // B frags for this jp (L2-hot btab); shared across all 4 mh groups
        const unsigned short* bp = bpb + (size_t)jp * (128 * 64);
        const s16x8 B0 = *(const s16x8*)&bp[lc * 64 + lg * 8];
        const s16x8 B1 = *(const s16x8*)&bp[(16 + lc) * 64 + lg * 8];
        const s16x8 B2 = *(const s16x8*)&bp[lc * 64 + 32 + lg * 8];
        const s16x8 B3 = *(const s16x8*)&bp[(16 + lc) * 64 + 32 + lg * 8];

        #pragma unroll
        for (int mh = 0; mh < 4; ++mh) {
            const int mbase = mh * 17 + lc;
            unsigned wa[4], wb[4];
            ABUILD(wa, lg * 2, lg * 2 + 1, mbase, colb2, 0)
            ABUILD(wb, r1a, r1b, mbase, colb2, 1)
            uint4 ai = { wa[0], wa[1], wa[2], wa[3] };
            uint4 bi = { wb[0], wb[1], wb[2], wb[3] };
            const s16x8 a0 = __builtin_bit_cast(s16x8, ai);
            const s16x8 a1 = __builtin_bit_cast(s16x8, bi);

            f32x4 acc[2];
            {
                f32x4 z = {0.f, 0.f, 0.f, 0.f};
                acc[0] = z; acc[1] = z;
            }
            acc[0] = __builtin_amdgcn_mfma_f32_16x16x32_bf16(a0, B0, acc[0], 0, 0, 0);
            acc[1] = __builtin_amdgcn_mfma_f32_16x16x32_bf16(a0, B1, acc[1], 0, 0, 0);
            acc[0] = __builtin_amdgcn_mfma_f32_16x16x32_bf16(a1, B2, acc[0], 0, 0, 0);
            acc[1] = __builtin_amdgcn_mfma_f32_16x16x32_bf16(a1, B3, acc[1], 0, 0, 0);

            // pool(quad)+relu+bf16 epilogue: one asm block, manual DPP hazards
            #pragma unroll
            for (int nf = 0; nf < 2; ++nf) {
                unsigned res, p1t, q0t, q1t;
                asm("v_cvt_pk_bf16_f32 %0, %4, %5\n\t"
                    "v_cvt_pk_bf16_f32 %1, %6, %7\n\t"
                    "s_nop 1\n\t"
                    "v_mov_b32 %2, %0 quad_perm:[1,0,3,2] row_mask:0xf bank_mask:0xf\n\t"
                    "v_mov_b32 %3, %1 quad_perm:[1,0,3,2] row_mask:0xf bank_mask:0xf\n\t"
                    "v_pk_max_i16 %0, %0, %2\n\t"
                    "v_pk_max_i16 %1, %1, %3\n\t"
                    "s_nop 1\n\t"
                    "v_mov_b32 %2, %0 quad_perm:[2,3,0,1] row_mask:0xf bank_mask:0xf\n\t"
                    "v_mov_b32 %3, %1 quad_perm:[2,3,0,1] row_mask:0xf bank_mask:0xf\n\t"
                    "v_pk_max_i16 %0, %0, %2\n\t"
                    "v_pk_max_i16 %1, %1, %3\n\t"
                    "v_cndmask_b32 %0, %0, %1, %9\n\t"
                    "v_alignbit_b32 %0, %0, %0, %8\n\t"
                    "v_pk_max_i16 %0, %0, 0"
                    : "=&v"(res), "=&v"(p1t), "=&v"(q0t), "=&v"(q1t)
                    : "v"(acc[nf][0]), "v"(acc[nf][1]),
                      "v"(acc[nf][2]), "v"(acc[nf][3]),
                      "v"(shamt), "s"(m2));
                pbuf[par][mh * 16 + lg * 4 + (lc & 3)][ocw * 8 + nf * 4 + (lc >> 2)] =
                    (unsigned short)res;
            }
        }
        // per-wave flush (NO barrier): lane = img, this wave's own 8 ocs,
        // its own parity buffer — same-wave readback only.
        *(s16x8*)&ybase[(size_t)jp * 32] = *(const s16x8*)&pbuf[par][lane][ocw * 8];
    }
#undef ABUILD
}

// ---------------------------------------------------------------------------
// k_conv: 3x3 SAME conv (32->64) + bias + ReLU + maxpool2, bf16 MFMA.
// ---------------------------------------------------------------------------
__global__ __launch_bounds__(256, 3) void k_conv(
    const unsigned short* __restrict__ y1g,  // half (2048,16,16,32) bf16
    const unsigned short* __restrict__ wt_g, // (9,64,40) bf16 packed
    const float* __restrict__ b_conv,        // (64,)
    unsigned short* __restrict__ p2)         // half (2048,64,8,8) bf16
{
    __shared__ __align__(16) unsigned short y1t[18][18][40]; // 25,920 B
    __shared__ __align__(16) unsigned short pbuf[4][1024];   //  8,192 B
    const int t = threadIdx.x;
    const int img = blockIdx.x;

    {
        const s16x8 z = {0, 0, 0, 0, 0, 0, 0, 0};
        unsigned short* p = &y1t[0][0][0];
        for (int i = t * 8; i < 18 * 18 * 40; i += 2048) *(s16x8*)(p + i) = z;
    }
    __syncthreads();
    {
        const int prr = t >> 4, pcc = t & 15;
        const unsigned short* src = y1g + ((size_t)img * 256 + t) * 32;
        unsigned short* d = &y1t[prr + 1][pcc + 1][0];
        #pragma unroll
        for (int ch = 0; ch < 4; ++ch)
            *(s16x8*)(d + ch * 8) = *(const s16x8*)(src + ch * 8);
    }
    __syncthreads();

    const int w = t >> 6, lane = t & 63;
    const int lc = lane & 15, lg = lane >> 4;

    f32x4 acc[4][4];
    #pragma unroll
    for (int mf = 0; mf < 4; ++mf)
        #pragma unroll
        for (int nf = 0; nf < 4; ++nf) {
            f32x4 zz = {0.f, 0.f, 0.f, 0.f};
            acc[mf][nf] = zz;
        }
    #pragma unroll
    for (int kk = 0; kk < 9; ++kk) {
        const int di = kk / 3, dj = kk % 3;
        s16x8 a[4], bb[4];
        #pragma unroll
        for (int nf = 0; nf < 4; ++nf)
            bb[nf] = *(const s16x8*)&wt_g[(kk * 64 + nf * 16 + lc) * 40 + lg * 8];
        #pragma unroll
        for (int mf = 0; mf < 4; ++mf)
            a[mf] = *(const s16x8*)&y1t[w * 4 + mf + di][lc + dj][lg * 8];
        #pragma unroll
        for (int mf = 0; mf < 4; ++mf)
            #pragma unroll
            for (int nf = 0; nf < 4; ++nf)
                acc[mf][nf] = __builtin_amdgcn_mfma_f32_16x16x32_bf16(
                    a[mf], bb[nf], acc[mf][nf], 0, 0, 0);
    }
    #pragma unroll
    for (int mfp = 0; mfp < 2; ++mfp) {
        #pragma unroll
        for (int nf = 0; nf < 4; ++nf) {
            const f32x4 u = acc[mfp * 2][nf], v = acc[mfp * 2 + 1][nf];
            const float bbv = b_conv[nf * 16 + lc];
            float q0 = fmaxf(fmaxf(u[0], u[1]), fmaxf(v[0], v[1]));
            float q1 = fmaxf(fmaxf(u[2], u[3]), fmaxf(v[2], v[3]));
            q0 = fmaxf(q0 + bbv, 0.f);
            q1 = fmaxf(q1 + bbv, 0.f);
            *(unsigned*)&pbuf[w][(nf * 16 + lc) * 16 + mfp * 8 + lg * 2] =
                (unsigned)f2bf(q0) | ((unsigned)f2bf(q1) << 16);
        }
    }
    #pragma unroll
    for (int jj = 0; jj < 2; ++jj) {
        const int u8 = jj * 64 + lane;
        const int oc = u8 >> 1, s = (u8 & 1) * 8;
        const s16x8 val = *(const s16x8*)&pbuf[w][u8 * 8];
        *(s16x8*)&p2[((size_t)img * 64 + oc) * 64 + w * 16 + s] = val;
    }
}

// ---------------------------------------------------------------------------
// k_fc1: SplitK=2, BM=64 x BN=64, 512 threads (8 waves, 16 waves/CU at
// 2 blocks/CU) — halves A re-read traffic vs BN=32 while keeping full
// latency-hiding wave count (R15's BN=64 failure was 8 waves/CU).
// fc1p[z][4096][256] f32 (bias in z=0, no relu).
// ---------------------------------------------------------------------------
__global__ __launch_bounds__(512) void k_fc1(
    const unsigned short* __restrict__ A,   // (4096,4096) bf16
    const unsigned short* __restrict__ Wb,  // (256,4096) bf16
    const float* __restrict__ bias, float* __restrict__ fc1p)
{
    __shared__ __align__(16) unsigned short As[64][72];
    __shared__ __align__(16) unsigned short Bs[64][72];
    const int t = threadIdx.x;
    const int m0 = blockIdx.x * 64, n0 = blockIdx.y * 64;
    const int z = blockIdx.z;
    const int w = t >> 6, lane = t & 63;
    const int lc = lane & 15, lg = lane >> 4;
    const int wr = w >> 2, wc = w & 3;     // wave tile: rows wr*32..+31, cols wc*16..+15
    f32x4 acc[2];
    {
        const float bv = (z == 0) ? bias[n0 + wc * 16 + lc] : 0.f;
        f32x4 a0 = {bv, bv, bv, bv};
        acc[0] = a0; acc[1] = a0;
    }
    const int kbase = z * 2048;
    const int r0 = t >> 3, ch0 = (t & 7) * 8;
    for (int k0 = kbase; k0 < kbase + 2048; k0 += 64) {
        *(s16x8*)&As[r0][ch0] = *(const s16x8*)&A[(size_t)(m0 + r0) * 4096 + k0 + ch0];
        *(s16x8*)&Bs[r0][ch0] = *(const s16x8*)&Wb[(size_t)(n0 + r0) * 4096 + k0 + ch0];
        __syncthreads();
        #pragma unroll
        for (int kh = 0; kh < 2; ++kh) {
            const s16x8 b = *(const s16x8*)&Bs[wc * 16 + lc][kh * 32 + lg * 8];
            #pragma unroll
            for (int mt = 0; mt < 2; ++mt) {
                const s16x8 a = *(const s16x8*)&As[wr * 32 + mt * 16 + lc][kh * 32 + lg * 8];
                acc[mt] = __builtin_amdgcn_mfma_f32_16x16x32_bf16(a, b, acc[mt], 0, 0, 0);
            }
        }
        __syncthreads();
    }
    #pragma unroll
    for (int mt = 0; mt < 2; ++mt) {
        const int n = n0 + wc * 16 + lc;
        #pragma unroll
        for (int q = 0; q < 4; ++q) {
            const int m = m0 + wr * 32 + mt * 16 + lg * 4 + q;
            fc1p[((size_t)z * 4096 + m) * 256 + n] = acc[mt][q];
        }
    }
}

// ---------------------------------------------------------------------------
// k_fc2: out = relu(fc1p[0]+fc1p[1]) @ w_fc2^T + b
// ---------------------------------------------------------------------------
__global__ __launch_bounds__(320) void k_fc2(
    const float* __restrict__ fc1p, const float* __restrict__ Wt,
    const float* __restrict__ bias, float* __restrict__ out)
{
    const int t = threadIdx.x;
    const int r = blockIdx.x * 32 + t / 10;
    const int n = t % 10;
    const float4* a0 = (const float4*)(fc1p + (size_t)r * 256);
    const float4* a1 = (const float4*)(fc1p + (size_t)(4096 + r) * 256);
    const float4* w = (const float4*)(Wt + (size_t)n * 256);
    float acc = bias[n];
    #pragma unroll 8
    for (int k = 0; k < 64; ++k) {
        const float4 u = a0[k], v = a1[k], wv = w[k];
        acc += fmaxf(u.x + v.x, 0.f) * wv.x + fmaxf(u.y + v.y, 0.f) * wv.y +
               fmaxf(u.z + v.z, 0.f) * wv.z + fmaxf(u.w + v.w, 0.f) * wv.w;
    }
    out[(size_t)r * 10 + n] = acc;
}

extern "C" void kernel_launch(void* const* d_in, const int* in_sizes, int n_in,
                              void* d_out, int out_size, void* d_ws, size_t ws_size,
                              hipStream_t stream)
{
    const float* x      = (const float*)d_in[0];
    const float* w_lc   = (const float*)d_in[1];
    const float* b_lc   = (const float*)d_in[2];
    const float* w_conv = (const float*)d_in[3];
    const float* b_conv = (const float*)d_in[4];
    const float* w_fc1  = (const float*)d_in[5];
    const float* b_fc1  = (const float*)d_in[6];
    const float* w_fc2  = (const float*)d_in[7];
    const float* b_fc2  = (const float*)d_in[8];
    float* out = (float*)d_out;

    // ws layout (69.3 MB total, proven):
    //   p2b  @ 0          : 33,554,432  (4096x4096 bf16)
    //   btab @ 16,777,216 : 4,194,304   (inside p2b 2nd half; clobbered by
    //                                    k_conv half1 only AFTER last btab read)
    //   y1g  @ 33,554,432 : 33,554,432  (half 2048x16x16x32 bf16)
    //   fc1p @ 33,554,432 : 8,388,608 f32 x2 partials (aliases y1g; post-conv)
    //   Wb   @ 67,108,864 : 2,097,152
    //   wt_g @ 69,206,016 : 92,160
    unsigned short* p2b  = (unsigned short*)d_ws;
    unsigned short* btab = (unsigned short*)((char*)d_ws + 16777216);
    unsigned short* y1g  = (unsigned short*)((char*)d_ws + 33554432);
    float*          fc1p = (float*)((char*)d_ws + 33554432);
    unsigned short* Wb   = (unsigned short*)((char*)d_ws + 67108864);
    unsigned short* wt_g = (unsigned short*)((char*)d_ws + 69206016);

    k_prep<<<1089, 256, 0, stream>>>(w_lc, b_lc, w_conv, w_fc1, btab, wt_g, Wb);
    for (int half = 0; half < 2; ++half) {
        k_lc<<<512, 512, 0, stream>>>(x + (size_t)half * 2048 * 3072, btab, y1g);
        k_conv<<<2048, 256, 0, stream>>>(y1g, wt_g, b_conv,
                                         p2b + (size_t)half * 2048 * 4096);
    }
    k_fc1<<<dim3(64, 4, 2), 512, 0, stream>>>(p2b, Wb, b_fc1, fc1p);
    k_fc2<<<128, 320, 0, stream>>>(fc1p, w_fc2, b_fc2, out);
}